// Round 1
// 387.791 us; speedup vs baseline: 1.0369x; 1.0369x over previous
//
#include <hip/hip_runtime.h>
#include <stdint.h>

// Problem constants
#define KCOMP 65536
#define DDIM  256
#define ODIM  256
#define BROWS 1024
#define NCB   512            // comp-blocks: KCOMP / 128 comps per block
#define NBLK  512            // main grid: one block per comp-block (no row split)
#define LOG2PI_TERM 235.2482645f   // 0.5 * D * ln(2*pi)

typedef float f32x4 __attribute__((ext_vector_type(4)));
typedef __bf16 bf16x8 __attribute__((ext_vector_type(8)));
typedef unsigned int u32;
typedef unsigned long long u64;
typedef unsigned short u16;

typedef __attribute__((address_space(1))) const u32 gconst_u32;
typedef __attribute__((address_space(3))) u32 lds_u32;

__device__ __forceinline__ u16 f2bf(float f) {
  u32 b = __float_as_uint(f);
  b += 0x7FFFu + ((b >> 16) & 1u);
  return (u16)(b >> 16);
}
// monotone float->u32 key (finalize only — main_gemm scores are all-negative
// so raw bits with unsigned-MIN are already order-correct)
__device__ __forceinline__ u32 fkey(float f) {
  u32 b = __float_as_uint(f);
  return b ^ ((b >> 31) ? 0xFFFFFFFFu : 0x80000000u);
}

// DPP row_ror:n (rotate within 16-lane rows) — used by finalize's reductions.
#define DPP_ROR1 0x121
#define DPP_ROR2 0x122
#define DPP_ROR4 0x124
#define DPP_ROR8 0x128

// ws layout (bytes). Total ~9 MB.
#define WS_A     0                          // 1 MB  A frag-linear [64 tile][16 cc][64 lane][16B]
#define WS_KEY   (1u << 20)                 // 8 MB  cand keys [1024 row][512 cb][4]

// ---------------------------------------------------------------------------
// Kernel 1: A features. kappa=2d -> x_d^2 ; kappa=2d+1 -> -2 x_d (MFMA A layout).
__global__ void prep_A(const float* __restrict__ x, u16* __restrict__ A) {
  int l = threadIdx.x & 63;
  int wv = threadIdx.x >> 6;
  int t = blockIdx.x;                 // m16 tile 0..63
  int row = t * 16 + (l & 15);
  for (int u = 0; u < 4; ++u) {
    int cc = wv * 4 + u;              // 0..15
    int d0 = cc * 16 + ((l >> 4) << 2);
    float4 xv = *(const float4*)(x + (size_t)row * DDIM + d0);
    float xs[4] = {xv.x, xv.y, xv.z, xv.w};
    uint4 v;
    u32 wds[4];
    for (int e = 0; e < 4; ++e)
      wds[e] = (u32)f2bf(xs[e] * xs[e]) | ((u32)f2bf(-2.0f * xs[e]) << 16);
    v.x = wds[0]; v.y = wds[1]; v.z = wds[2]; v.w = wds[3];
    *(uint4*)(A + ((size_t)(t * 16 + cc) * 64 + l) * 8) = v;
  }
}

// ---------------------------------------------------------------------------
// Kernel 2: main GEMM + fused W-conversion + fused selection.
// Grid 512 = one block per 128 comps; block sweeps ALL 1024 rows.
// ROUND-6 CHANGE (selection off the DPP path): MFMA operands are SWAPPED
// (mfma(W, A)) so the output tile has comp = (lane>>4)*4+reg (in-register)
// and x-row = lane&15. Per-lane top-2-of-8 register tree + 2 shfl_xor merge
// steps replaces the 8x 4-step DPP row_ror reduction. -0.5 is pre-folded
// into the bf16 W values and myc is folded into the accumulator init, so
// the MFMA result IS the selection score (no per-score fmaf).
__global__ __launch_bounds__(256, 2)
void main_gemm(const u16* __restrict__ A_ws, const float* __restrict__ mean,
               const float* __restrict__ stdd, u32* __restrict__ ckey) {
  // union: [0,66560) = per-wave conversion scratch (4 x 16640 B) in prologue,
  //        [0,65536) = A double-buffer (2 bufs x 32 cells x 1 KB) in main loop
  __shared__ __align__(16) char lds_raw[66560];
  __shared__ u32 wsel[2][32][9];       // [buf][row][4 waves x 2 + pad]
  int tid = threadIdx.x, l = tid & 63, w = tid >> 6;
  int nb = blockIdx.x;                 // comp-block 0..511
  int g0 = nb * 8 + w * 2;             // two 16-comp groups per wave
  int p = l & 15, q = l >> 4;

  // per-lane comp ids for the swapped layout: cid = w*32 | gs*16 | q*4 | i
  u32 kidv[8];
#pragma unroll
  for (int gs = 0; gs < 2; ++gs)
#pragma unroll
    for (int i = 0; i < 4; ++i)
      kidv[gs * 4 + i] = (u32)(w * 32 + gs * 16 + q * 4 + i);

  // ---- prologue: build wf[2][16] B-frags (pre-scaled by -0.5) + mycv ----
  bf16x8 wf[2][16];
  float myc[2];
  f32x4 mycv[2];
  {
    u32* scr = (u32*)(lds_raw + w * 16640);  // [16 comps][260 dwords] padded
#pragma unroll
    for (int gs = 0; gs < 2; ++gs) {
      int comp = (g0 + gs) * 16 + p;
      const float* mrow = mean + (size_t)comp * DDIM + q * 64;
      const float* srow = stdd + (size_t)comp * DDIM + q * 64;
      float gsum = 0.f;
#pragma unroll
      for (int i = 0; i < 16; ++i) {
        float4 m4 = *(const float4*)(mrow + 4 * i);
        float4 s4 = *(const float4*)(srow + 4 * i);
        float ms[4] = {m4.x, m4.y, m4.z, m4.w};
        float ss[4] = {s4.x, s4.y, s4.z, s4.w};
        u32 wd[4];
#pragma unroll
        for (int e = 0; e < 4; ++e) {
          float iv = __builtin_amdgcn_rcpf(ss[e] * ss[e]);
          float miv = ms[e] * iv;
          // store -0.5*iv | -0.5*miv so dot(A,W) = -0.5*quad directly
          wd[e] = (u32)f2bf(-0.5f * iv) | ((u32)f2bf(-0.5f * miv) << 16);
          gsum -= 0.5f * ms[e] * miv + __logf(ss[e]);
        }
        uint4 v; v.x = wd[0]; v.y = wd[1]; v.z = wd[2]; v.w = wd[3];
        *(uint4*)(scr + p * 260 + q * 64 + i * 4) = v;   // [comp][dim] packed
      }
      gsum += __shfl_xor(gsum, 16);    // sum the 4 quarter-partials of comp p
      gsum += __shfl_xor(gsum, 32);
      myc[gs] = gsum - LOG2PI_TERM;
      // frag read (wave-local; in-order LDS): lane l -> comp p, dims cc*16+q*4
#pragma unroll
      for (int cc = 0; cc < 16; ++cc)
        wf[gs][cc] = *(const bf16x8*)(scr + p * 260 + cc * 16 + q * 4);
    }
    // redistribute myc: lane (q,p) needs myc of comps q*4+i (held by lane q*4+i)
#pragma unroll
    for (int gs = 0; gs < 2; ++gs)
#pragma unroll
      for (int i = 0; i < 4; ++i)
        mycv[gs][i] = __shfl(myc[gs], q * 4 + i);
  }
  __syncthreads();                     // scratch region now reused as Ash

#define ASHP(B, CELL) (lds_raw + ((size_t)(B) * 32 + (CELL)) * 1024)

  // stage S (2 m16-tiles = 32 cells of 1 KB) into buf B; wave stages 8 cells
#define ISSUE(S, B)                                                           \
  {                                                                           \
    _Pragma("unroll")                                                         \
    for (int u = 0; u < 8; ++u) {                                             \
      int cell = w * 8 + u;                                                   \
      const u16* gsrc = A_ws +                                                \
        ((size_t)((S) * 2 + (cell >> 4)) * 16 + (cell & 15)) * 512            \
        + (size_t)l * 8;                                                      \
      __builtin_amdgcn_global_load_lds((gconst_u32*)gsrc,                     \
          (lds_u32*)ASHP(B, cell), 16, 0, 0);                                 \
    }                                                                         \
  }

  // merge 8 wsel keys (min = best) -> 4 smallest for 32 rows; emit inverted
#define MERGE_EMIT(ST, B)                                                     \
  {                                                                           \
    int r = tid;                                                              \
    u32 top[4] = {~0u, ~0u, ~0u, ~0u};                                        \
    _Pragma("unroll")                                                         \
    for (int j = 0; j < 8; ++j) {                                             \
      u32 key = wsel[B][r][j];                                                \
      if (key < top[3]) {                                                     \
        top[3] = key;                                                         \
        for (int z = 3; z > 0 && top[z] < top[z - 1]; --z) {                  \
          u32 tt = top[z]; top[z] = top[z - 1]; top[z - 1] = tt;              \
        }                                                                     \
      }                                                                       \
    }                                                                         \
    int rowg = (ST) * 32 + r;                                                 \
    uint4 ov; ov.x = ~top[0]; ov.y = ~top[1]; ov.z = ~top[2]; ov.w = ~top[3]; \
    *(uint4*)&ckey[((size_t)rowg * NCB + nb) * 4] = ov;                       \
  }

  ISSUE(0, 0)
  for (int s = 0; s < 32; ++s) {
    int pb = s & 1;
    __syncthreads();                   // buf pb staged; wsel[pb^1] complete
    if (s < 31) ISSUE(s + 1, pb ^ 1)
    if (s > 0 && tid < 32) MERGE_EMIT(s - 1, pb ^ 1)

    f32x4 ac[2][2];                    // [tile][comp-group]; init = myc
#pragma unroll
    for (int t = 0; t < 2; ++t) {
      ac[t][0] = mycv[0];
      ac[t][1] = mycv[1];
    }
#pragma unroll
    for (int cc = 0; cc < 16; ++cc) {
      bf16x8 a0 = *(const bf16x8*)(ASHP(pb, cc) + (size_t)l * 16);
      bf16x8 a1 = *(const bf16x8*)(ASHP(pb, 16 + cc) + (size_t)l * 16);
      // SWAPPED operands: W as A-operand (comps = M), rows as B-operand (N)
      ac[0][0] = __builtin_amdgcn_mfma_f32_16x16x32_bf16(wf[0][cc], a0, ac[0][0], 0, 0, 0);
      ac[0][1] = __builtin_amdgcn_mfma_f32_16x16x32_bf16(wf[1][cc], a0, ac[0][1], 0, 0, 0);
      ac[1][0] = __builtin_amdgcn_mfma_f32_16x16x32_bf16(wf[0][cc], a1, ac[1][0], 0, 0, 0);
      ac[1][1] = __builtin_amdgcn_mfma_f32_16x16x32_bf16(wf[1][cc], a1, ac[1][1], 0, 0, 0);
    }

    // selection: lane holds 8 comps (2 gs x 4 reg) of x-row t*16+p.
    // scores are the ac values directly (all <= -235 < 0): unsigned MIN = best.
#define UMIN(a, b) ((a) < (b) ? (a) : (b))
#define UMAX(a, b) ((a) < (b) ? (b) : (a))
#pragma unroll
    for (int t = 0; t < 2; ++t) {
      u32 k0 = (__float_as_uint(ac[t][0][0]) & 0xFFFFFF00u) | kidv[0];
      u32 k1 = (__float_as_uint(ac[t][0][1]) & 0xFFFFFF00u) | kidv[1];
      u32 k2 = (__float_as_uint(ac[t][0][2]) & 0xFFFFFF00u) | kidv[2];
      u32 k3 = (__float_as_uint(ac[t][0][3]) & 0xFFFFFF00u) | kidv[3];
      u32 k4 = (__float_as_uint(ac[t][1][0]) & 0xFFFFFF00u) | kidv[4];
      u32 k5 = (__float_as_uint(ac[t][1][1]) & 0xFFFFFF00u) | kidv[5];
      u32 k6 = (__float_as_uint(ac[t][1][2]) & 0xFFFFFF00u) | kidv[6];
      u32 k7 = (__float_as_uint(ac[t][1][3]) & 0xFFFFFF00u) | kidv[7];
      // in-register top-2-of-8 (merge tree of sorted pairs)
      u32 l0 = UMIN(k0, k1), h0 = UMAX(k0, k1);
      u32 l1 = UMIN(k2, k3), h1 = UMAX(k2, k3);
      u32 l2 = UMIN(k4, k5), h2 = UMAX(k4, k5);
      u32 l3 = UMIN(k6, k7), h3 = UMAX(k6, k7);
      u32 A1 = UMIN(l0, l1), A2 = UMIN(UMAX(l0, l1), UMIN(h0, h1));
      u32 B1 = UMIN(l2, l3), B2 = UMIN(UMAX(l2, l3), UMIN(h2, h3));
      u32 m1 = UMIN(A1, B1), m2 = UMIN(UMAX(A1, B1), UMIN(A2, B2));
      // merge across the 4 q-lanes holding the same x-row: xor16 then xor32
      {
        u32 o1 = (u32)__shfl_xor((int)m1, 16);
        u32 o2 = (u32)__shfl_xor((int)m2, 16);
        u32 lo = UMIN(m1, o1), hi = UMAX(m1, o1), mn = UMIN(m2, o2);
        m1 = lo; m2 = UMIN(hi, mn);
      }
      {
        u32 o1 = (u32)__shfl_xor((int)m1, 32);
        u32 o2 = (u32)__shfl_xor((int)m2, 32);
        u32 lo = UMIN(m1, o1), hi = UMAX(m1, o1), mn = UMIN(m2, o2);
        m1 = lo; m2 = UMIN(hi, mn);
      }
      if (q == 0) {
        int r = t * 16 + p;
        wsel[pb][r][w * 2] = m1;
        wsel[pb][r][w * 2 + 1] = m2;
      }
    }
#undef UMIN
#undef UMAX
  }
  __syncthreads();
  if (tid < 32) MERGE_EMIT(31, 1)
#undef ISSUE
#undef MERGE_EMIT
#undef ASHP
}

// ---------------------------------------------------------------------------
// Kernel 3: per-row finalize. 2048 keys -> 4 parallel per-wave exact top-16
// via u32 ext-keys + DPP/shfl arg-max; exact fp32 lp for 64; exact top-32 +
// softmax; weighted gather.
__global__ __launch_bounds__(256)
void finalize(const float* __restrict__ x, const float* __restrict__ mean,
              const float* __restrict__ stdd, const float* __restrict__ outs,
              const u32* __restrict__ ckey, float* __restrict__ out) {
  __shared__ u32 cksh[2048];
  __shared__ float xr[256];
  __shared__ float part[256];
  __shared__ int selk[64];
  __shared__ float ew[32];
  __shared__ int kf[32];
  __shared__ float invs_sh;
  int tid = threadIdx.x, l = tid & 63, v = tid >> 6;
  int row = blockIdx.x;

  for (int i = tid; i < 2048; i += 256)
    cksh[i] = ckey[(size_t)row * 2048 + i];
  xr[tid] = x[(size_t)row * DDIM + tid];
  __syncthreads();

  // 64-lane max reduce on u32 (4 DPP rotations + 2 shfl)
#define REDUCE_MAX(m)                                                         \
  {                                                                           \
    u32 o;                                                                    \
    o = (u32)__builtin_amdgcn_mov_dpp((int)m, DPP_ROR1, 0xf, 0xf, false);     \
    m = m > o ? m : o;                                                        \
    o = (u32)__builtin_amdgcn_mov_dpp((int)m, DPP_ROR2, 0xf, 0xf, false);     \
    m = m > o ? m : o;                                                        \
    o = (u32)__builtin_amdgcn_mov_dpp((int)m, DPP_ROR4, 0xf, 0xf, false);     \
    m = m > o ? m : o;                                                        \
    o = (u32)__builtin_amdgcn_mov_dpp((int)m, DPP_ROR8, 0xf, 0xf, false);     \
    m = m > o ? m : o;                                                        \
    o = (u32)__shfl_xor((int)m, 16); m = m > o ? m : o;                       \
    o = (u32)__shfl_xor((int)m, 32); m = m > o ? m : o;                       \
  }

  {  // wave v: exact top-16 of its 512 cands
    u32 ext[8];
#pragma unroll
    for (int i = 0; i < 8; ++i) {
      int j = v * 512 + i * 64 + l;
      ext[i] = (cksh[j] & 0xFFFFFE00u) | ((u32)l << 3) | (u32)i;
    }
#define CSW(a, b) { if (ext[a] < ext[b]) { u32 t = ext[a]; ext[a] = ext[b]; ext[b] = t; } }
    CSW(0,1) CSW(2,3) CSW(4,5) CSW(6,7)
    CSW(0,2) CSW(1,3) CSW(4,6) CSW(5,7)
    CSW(1,2) CSW(5,6)
    CSW(0,4) CSW(1,5) CSW(2,6) CSW(3,7)
    CSW(2,4) CSW(3,5)
    CSW(1,2) CSW(3,4) CSW(5,6)
#undef CSW
    for (int it = 0; it < 16; ++it) {
      u32 m = ext[0];
      REDUCE_MAX(m)
      if (m == ext[0]) {
#pragma unroll
        for (int z = 0; z < 7; ++z) ext[z] = ext[z + 1];
        ext[7] = 0;
      }
      if (l == 0) {
        int wl = (int)((m >> 3) & 63u), wi = (int)(m & 7u);
        int j = v * 512 + wi * 64 + wl;
        selk[v * 16 + it] = (int)((u32)(j >> 2) * 128u + (~cksh[j] & 0x7Fu));
      }
    }
  }
  __syncthreads();

  {  // exact fp32 lp for 64 cands, 4 threads each
    int j = tid >> 2, qq = tid & 3;
    int k = selk[j];
    const float* mr = mean + (size_t)k * DDIM + qq * 64;
    const float* sr = stdd + (size_t)k * DDIM + qq * 64;
    float s2 = 0.f, ls = 0.f;
    for (int i = 0; i < 16; ++i) {
      float4 m4 = *(const float4*)(mr + 4 * i);
      float4 s4 = *(const float4*)(sr + 4 * i);
      float4 x4 = *(const float4*)(&xr[qq * 64 + 4 * i]);
      { float is = 1.f / s4.x; float df = (x4.x - m4.x) * is; s2 += df * df; ls += __logf(s4.x); }
      { float is = 1.f / s4.y; float df = (x4.y - m4.y) * is; s2 += df * df; ls += __logf(s4.y); }
      { float is = 1.f / s4.z; float df = (x4.z - m4.z) * is; s2 += df * df; ls += __logf(s4.z); }
      { float is = 1.f / s4.w; float df = (x4.w - m4.w) * is; s2 += df * df; ls += __logf(s4.w); }
    }
    part[tid] = -0.5f * s2 - ls;
  }
  __syncthreads();

  if (tid < 64) {                      // exact top-32 + softmax (wave 0)
    float lp0 = part[l * 4] + part[l * 4 + 1] + part[l * 4 + 2] +
                part[l * 4 + 3] - LOG2PI_TERM;
    u32 ext = (fkey(lp0) & 0xFFFFFFC0u) | (u32)l;
    float maxlp = 0.f, ssum = 0.f;
    for (int it = 0; it < 32; ++it) {
      u32 m = ext;
      REDUCE_MAX(m)
      int j = (int)(m & 63u);
      u32 vb = m & 0xFFFFFFC0u;
      vb ^= (vb >> 31) ? 0x80000000u : 0xFFFFFFFFu;
      float lp = __uint_as_float(vb);
      if (it == 0) maxlp = lp;
      float e = __expf(lp - maxlp);
      ssum += e;
      if (l == 0) { ew[it] = e; kf[it] = selk[j]; }
      if (j == l) ext = 0;
    }
    if (l == 0) invs_sh = 1.0f / ssum;
  }
  __syncthreads();
#undef REDUCE_MAX

  {  // weighted gather: one output element per thread
    float a = 0.f;
    for (int i = 0; i < 32; ++i)
      a += ew[i] * outs[(size_t)kf[i] * ODIM + tid];
    out[(size_t)row * ODIM + tid] = a * invs_sh;
  }
}

// ---------------------------------------------------------------------------
extern "C" void kernel_launch(void* const* d_in, const int* in_sizes, int n_in,
                              void* d_out, int out_size, void* d_ws, size_t ws_size,
                              hipStream_t stream) {
  const float* x = (const float*)d_in[0];
  const float* mean = (const float*)d_in[1];
  const float* stdd = (const float*)d_in[2];
  const float* outs = (const float*)d_in[3];
  char* ws = (char*)d_ws;
  u16* A_ws = (u16*)(ws + WS_A);
  u32* ckey = (u32*)(ws + WS_KEY);

  prep_A<<<64, 256, 0, stream>>>(x, A_ws);
  main_gemm<<<NBLK, 256, 0, stream>>>(A_ws, mean, stdd, ckey);
  finalize<<<BROWS, 256, 0, stream>>>(x, mean, stdd, outs, ckey,
                                      (float*)d_out);
}

// Round 2
// 379.731 us; speedup vs baseline: 1.0589x; 1.0212x over previous
//
#include <hip/hip_runtime.h>
#include <stdint.h>

// Problem constants
#define KCOMP 65536
#define DDIM  256
#define ODIM  256
#define BROWS 1024
#define NCB   512            // comp-blocks: KCOMP / 128 comps per block
#define NBLK  512            // main grid: one block per comp-block (no row split)
#define LOG2PI_TERM 235.2482645f   // 0.5 * D * ln(2*pi)

typedef float f32x4 __attribute__((ext_vector_type(4)));
typedef __bf16 bf16x8 __attribute__((ext_vector_type(8)));
typedef unsigned int u32;
typedef unsigned long long u64;
typedef unsigned short u16;

typedef __attribute__((address_space(1))) const u32 gconst_u32;
typedef __attribute__((address_space(3))) u32 lds_u32;

__device__ __forceinline__ u16 f2bf(float f) {
  u32 b = __float_as_uint(f);
  b += 0x7FFFu + ((b >> 16) & 1u);
  return (u16)(b >> 16);
}
// monotone float->u32 key (finalize only — main_gemm scores are all-negative
// so raw bits with unsigned-MIN are already order-correct)
__device__ __forceinline__ u32 fkey(float f) {
  u32 b = __float_as_uint(f);
  return b ^ ((b >> 31) ? 0xFFFFFFFFu : 0x80000000u);
}

// DPP row_ror:n (rotate within 16-lane rows) — used by finalize's reductions.
#define DPP_ROR1 0x121
#define DPP_ROR2 0x122
#define DPP_ROR4 0x124
#define DPP_ROR8 0x128

// ws layout (bytes). Total ~9 MB.
#define WS_A     0                          // 1 MB  A frag-linear [64 tile][16 cc][64 lane][16B]
#define WS_KEY   (1u << 20)                 // 8 MB  cand keys [1024 row][512 cb][4]

// ---------------------------------------------------------------------------
// Kernel 1: A features. kappa=2d -> x_d^2 ; kappa=2d+1 -> -2 x_d (MFMA A layout).
__global__ void prep_A(const float* __restrict__ x, u16* __restrict__ A) {
  int l = threadIdx.x & 63;
  int wv = threadIdx.x >> 6;
  int t = blockIdx.x;                 // m16 tile 0..63
  int row = t * 16 + (l & 15);
  for (int u = 0; u < 4; ++u) {
    int cc = wv * 4 + u;              // 0..15
    int d0 = cc * 16 + ((l >> 4) << 2);
    float4 xv = *(const float4*)(x + (size_t)row * DDIM + d0);
    float xs[4] = {xv.x, xv.y, xv.z, xv.w};
    uint4 v;
    u32 wds[4];
    for (int e = 0; e < 4; ++e)
      wds[e] = (u32)f2bf(xs[e] * xs[e]) | ((u32)f2bf(-2.0f * xs[e]) << 16);
    v.x = wds[0]; v.y = wds[1]; v.z = wds[2]; v.w = wds[3];
    *(uint4*)(A + ((size_t)(t * 16 + cc) * 64 + l) * 8) = v;
  }
}

// ---------------------------------------------------------------------------
// Kernel 2: main GEMM + fused W-conversion + fused selection.
// Grid 512 = one block per 128 comps; block sweeps ALL 1024 rows.
// ROUND-7 CHANGE (occupancy): blocks are now 512 threads (8 waves), each wave
// owns 16 comps (wf[1][16] = 64 regs instead of 128). Unified regs/wave drop
// to ~120 -> 4 waves/SIMD; LDS 69 KB/block x 2 blocks/CU -> 16 waves/CU
// (occupancy 21.7% -> ~45%). Accepted cost: each wave reads the full 32-row
// A-stage for half the MFMAs (total LDS read 2 GB -> 4 GB, floor ~58 us) in
// exchange for 2x wave-level latency hiding. Selection shrinks to a
// top-2-of-4 register tree; wsel widens to 16 cands/row (more robust).
// s_setprio(1) wraps the MFMA cluster (4 waves/SIMD = role diversity, T5).
__global__ __launch_bounds__(512, 4)
void main_gemm(const u16* __restrict__ A_ws, const float* __restrict__ mean,
               const float* __restrict__ stdd, u32* __restrict__ ckey) {
  // union: [0,66560) = per-wave conversion scratch (8 x 8320 B) in prologue,
  //        [0,65536) = A double-buffer (2 bufs x 32 cells x 1 KB) in main loop
  __shared__ __align__(16) char lds_raw[66560];
  __shared__ u32 wsel[2][32][17];      // [buf][row][8 waves x 2 + pad]
  int tid = threadIdx.x, l = tid & 63, w = tid >> 6;   // w in [0,8)
  int nb = blockIdx.x;                 // comp-block 0..511
  int p = l & 15, q = l >> 4;

  u32 kid0 = (u32)(w * 16 + q * 4);    // local comp id base for this lane

  // ---- prologue: build wf[16] B-frags (pre-scaled by -0.5) + mycv ----
  // two rounds of 8 comps each through an 8-comp scratch (8320 B/wave)
  bf16x8 wf[16];
  float myc0;
  f32x4 mycv;
  {
    u32* scr = (u32*)(lds_raw + w * 8320);   // [8 comps][260 dwords] padded
    int p8 = l & 7, q8 = l >> 3;             // q8 in [0,8): 32-dim eighth
#pragma unroll
    for (int rr = 0; rr < 2; ++rr) {
      int comp = (nb * 8 + w) * 16 + rr * 8 + p8;
      const float* mrow = mean + (size_t)comp * DDIM + q8 * 32;
      const float* srow = stdd + (size_t)comp * DDIM + q8 * 32;
      float gsum = 0.f;
#pragma unroll
      for (int i = 0; i < 8; ++i) {
        float4 m4 = *(const float4*)(mrow + 4 * i);
        float4 s4 = *(const float4*)(srow + 4 * i);
        float ms[4] = {m4.x, m4.y, m4.z, m4.w};
        float ss[4] = {s4.x, s4.y, s4.z, s4.w};
        u32 wd[4];
#pragma unroll
        for (int e = 0; e < 4; ++e) {
          float iv = __builtin_amdgcn_rcpf(ss[e] * ss[e]);
          float miv = ms[e] * iv;
          // store -0.5*iv | -0.5*miv so dot(A,W) = -0.5*quad directly
          wd[e] = (u32)f2bf(-0.5f * iv) | ((u32)f2bf(-0.5f * miv) << 16);
          gsum -= 0.5f * ms[e] * miv + __logf(ss[e]);
        }
        uint4 v; v.x = wd[0]; v.y = wd[1]; v.z = wd[2]; v.w = wd[3];
        *(uint4*)(scr + p8 * 260 + q8 * 32 + i * 4) = v;   // [comp][dim]
      }
      // sum the 8 dim-eighth partials of comp p8 (lanes sharing l&7)
      gsum += __shfl_xor(gsum, 8);
      gsum += __shfl_xor(gsum, 16);
      gsum += __shfl_xor(gsum, 32);
      // lanes whose comp (p = l&15) lives in this round read their frags now
      // (wave-local in-order LDS; round rr+1 overwrites the scratch)
      if ((p >> 3) == rr) {
        myc0 = gsum - LOG2PI_TERM;
#pragma unroll
        for (int cc = 0; cc < 16; ++cc)
          wf[cc] = *(const bf16x8*)(scr + (p & 7) * 260 + cc * 16 + q * 4);
      }
    }
    // redistribute myc: lane (q,p) needs myc of comps q*4+i (held by lane q*4+i)
#pragma unroll
    for (int i = 0; i < 4; ++i)
      mycv[i] = __shfl(myc0, q * 4 + i);
  }
  __syncthreads();                     // scratch region now reused as Ash

#define ASHP(B, CELL) (lds_raw + ((size_t)(B) * 32 + (CELL)) * 1024)

  // stage S (2 m16-tiles = 32 cells of 1 KB) into buf B; wave stages 4 cells
#define ISSUE(S, B)                                                           \
  {                                                                           \
    _Pragma("unroll")                                                         \
    for (int u = 0; u < 4; ++u) {                                             \
      int cell = w * 4 + u;                                                   \
      const u16* gsrc = A_ws +                                                \
        ((size_t)((S) * 2 + (cell >> 4)) * 16 + (cell & 15)) * 512            \
        + (size_t)l * 8;                                                      \
      __builtin_amdgcn_global_load_lds((gconst_u32*)gsrc,                     \
          (lds_u32*)ASHP(B, cell), 16, 0, 0);                                 \
    }                                                                         \
  }

  // merge 16 wsel keys (min = best) -> 4 smallest for 32 rows; emit inverted
#define MERGE_EMIT(ST, B)                                                     \
  {                                                                           \
    int r = tid;                                                              \
    u32 top[4] = {~0u, ~0u, ~0u, ~0u};                                        \
    _Pragma("unroll")                                                         \
    for (int j = 0; j < 16; ++j) {                                            \
      u32 key = wsel[B][r][j];                                                \
      if (key < top[3]) {                                                     \
        top[3] = key;                                                         \
        for (int z = 3; z > 0 && top[z] < top[z - 1]; --z) {                  \
          u32 tt = top[z]; top[z] = top[z - 1]; top[z - 1] = tt;              \
        }                                                                     \
      }                                                                       \
    }                                                                         \
    int rowg = (ST) * 32 + r;                                                 \
    uint4 ov; ov.x = ~top[0]; ov.y = ~top[1]; ov.z = ~top[2]; ov.w = ~top[3]; \
    *(uint4*)&ckey[((size_t)rowg * NCB + nb) * 4] = ov;                       \
  }

  ISSUE(0, 0)
  for (int s = 0; s < 32; ++s) {
    int pb = s & 1;
    __syncthreads();                   // buf pb staged; wsel[pb^1] complete
    if (s < 31) ISSUE(s + 1, pb ^ 1)
    if (s > 0 && tid < 32) MERGE_EMIT(s - 1, pb ^ 1)

    f32x4 ac[2];                       // [tile]; init = myc (per-comp const)
    ac[0] = mycv;
    ac[1] = mycv;
    __builtin_amdgcn_s_setprio(1);
#pragma unroll
    for (int cc = 0; cc < 16; ++cc) {
      bf16x8 a0 = *(const bf16x8*)(ASHP(pb, cc) + (size_t)l * 16);
      bf16x8 a1 = *(const bf16x8*)(ASHP(pb, 16 + cc) + (size_t)l * 16);
      // SWAPPED operands: W as A-operand (comps = M), rows as B-operand (N)
      ac[0] = __builtin_amdgcn_mfma_f32_16x16x32_bf16(wf[cc], a0, ac[0], 0, 0, 0);
      ac[1] = __builtin_amdgcn_mfma_f32_16x16x32_bf16(wf[cc], a1, ac[1], 0, 0, 0);
    }
    __builtin_amdgcn_s_setprio(0);

    // selection: lane holds 4 comps (q*4+i) of x-row t*16+p.
    // scores are the ac values directly (all <= -235 < 0): unsigned MIN = best.
#define UMIN(a, b) ((a) < (b) ? (a) : (b))
#define UMAX(a, b) ((a) < (b) ? (b) : (a))
#pragma unroll
    for (int t = 0; t < 2; ++t) {
      u32 k0 = (__float_as_uint(ac[t][0]) & 0xFFFFFF00u) | (kid0 + 0);
      u32 k1 = (__float_as_uint(ac[t][1]) & 0xFFFFFF00u) | (kid0 + 1);
      u32 k2 = (__float_as_uint(ac[t][2]) & 0xFFFFFF00u) | (kid0 + 2);
      u32 k3 = (__float_as_uint(ac[t][3]) & 0xFFFFFF00u) | (kid0 + 3);
      // in-register top-2-of-4
      u32 l0 = UMIN(k0, k1), h0 = UMAX(k0, k1);
      u32 l1 = UMIN(k2, k3), h1 = UMAX(k2, k3);
      u32 m1 = UMIN(l0, l1), m2 = UMIN(UMAX(l0, l1), UMIN(h0, h1));
      // merge across the 4 q-lanes holding the same x-row: xor16 then xor32
      {
        u32 o1 = (u32)__shfl_xor((int)m1, 16);
        u32 o2 = (u32)__shfl_xor((int)m2, 16);
        u32 lo = UMIN(m1, o1), hi = UMAX(m1, o1), mn = UMIN(m2, o2);
        m1 = lo; m2 = UMIN(hi, mn);
      }
      {
        u32 o1 = (u32)__shfl_xor((int)m1, 32);
        u32 o2 = (u32)__shfl_xor((int)m2, 32);
        u32 lo = UMIN(m1, o1), hi = UMAX(m1, o1), mn = UMIN(m2, o2);
        m1 = lo; m2 = UMIN(hi, mn);
      }
      if (q == 0) {
        int r = t * 16 + p;
        wsel[pb][r][w * 2] = m1;
        wsel[pb][r][w * 2 + 1] = m2;
      }
    }
#undef UMIN
#undef UMAX
  }
  __syncthreads();
  if (tid < 32) MERGE_EMIT(31, 1)
#undef ISSUE
#undef MERGE_EMIT
#undef ASHP
}

// ---------------------------------------------------------------------------
// Kernel 3: per-row finalize. 2048 keys -> 4 parallel per-wave exact top-16
// via u32 ext-keys + DPP/shfl arg-max; exact fp32 lp for 64; exact top-32 +
// softmax; weighted gather.
__global__ __launch_bounds__(256)
void finalize(const float* __restrict__ x, const float* __restrict__ mean,
              const float* __restrict__ stdd, const float* __restrict__ outs,
              const u32* __restrict__ ckey, float* __restrict__ out) {
  __shared__ u32 cksh[2048];
  __shared__ float xr[256];
  __shared__ float part[256];
  __shared__ int selk[64];
  __shared__ float ew[32];
  __shared__ int kf[32];
  __shared__ float invs_sh;
  int tid = threadIdx.x, l = tid & 63, v = tid >> 6;
  int row = blockIdx.x;

  for (int i = tid; i < 2048; i += 256)
    cksh[i] = ckey[(size_t)row * 2048 + i];
  xr[tid] = x[(size_t)row * DDIM + tid];
  __syncthreads();

  // 64-lane max reduce on u32 (4 DPP rotations + 2 shfl)
#define REDUCE_MAX(m)                                                         \
  {                                                                           \
    u32 o;                                                                    \
    o = (u32)__builtin_amdgcn_mov_dpp((int)m, DPP_ROR1, 0xf, 0xf, false);     \
    m = m > o ? m : o;                                                        \
    o = (u32)__builtin_amdgcn_mov_dpp((int)m, DPP_ROR2, 0xf, 0xf, false);     \
    m = m > o ? m : o;                                                        \
    o = (u32)__builtin_amdgcn_mov_dpp((int)m, DPP_ROR4, 0xf, 0xf, false);     \
    m = m > o ? m : o;                                                        \
    o = (u32)__builtin_amdgcn_mov_dpp((int)m, DPP_ROR8, 0xf, 0xf, false);     \
    m = m > o ? m : o;                                                        \
    o = (u32)__shfl_xor((int)m, 16); m = m > o ? m : o;                       \
    o = (u32)__shfl_xor((int)m, 32); m = m > o ? m : o;                       \
  }

  {  // wave v: exact top-16 of its 512 cands
    u32 ext[8];
#pragma unroll
    for (int i = 0; i < 8; ++i) {
      int j = v * 512 + i * 64 + l;
      ext[i] = (cksh[j] & 0xFFFFFE00u) | ((u32)l << 3) | (u32)i;
    }
#define CSW(a, b) { if (ext[a] < ext[b]) { u32 t = ext[a]; ext[a] = ext[b]; ext[b] = t; } }
    CSW(0,1) CSW(2,3) CSW(4,5) CSW(6,7)
    CSW(0,2) CSW(1,3) CSW(4,6) CSW(5,7)
    CSW(1,2) CSW(5,6)
    CSW(0,4) CSW(1,5) CSW(2,6) CSW(3,7)
    CSW(2,4) CSW(3,5)
    CSW(1,2) CSW(3,4) CSW(5,6)
#undef CSW
    for (int it = 0; it < 16; ++it) {
      u32 m = ext[0];
      REDUCE_MAX(m)
      if (m == ext[0]) {
#pragma unroll
        for (int z = 0; z < 7; ++z) ext[z] = ext[z + 1];
        ext[7] = 0;
      }
      if (l == 0) {
        int wl = (int)((m >> 3) & 63u), wi = (int)(m & 7u);
        int j = v * 512 + wi * 64 + wl;
        selk[v * 16 + it] = (int)((u32)(j >> 2) * 128u + (~cksh[j] & 0x7Fu));
      }
    }
  }
  __syncthreads();

  {  // exact fp32 lp for 64 cands, 4 threads each
    int j = tid >> 2, qq = tid & 3;
    int k = selk[j];
    const float* mr = mean + (size_t)k * DDIM + qq * 64;
    const float* sr = stdd + (size_t)k * DDIM + qq * 64;
    float s2 = 0.f, ls = 0.f;
    for (int i = 0; i < 16; ++i) {
      float4 m4 = *(const float4*)(mr + 4 * i);
      float4 s4 = *(const float4*)(sr + 4 * i);
      float4 x4 = *(const float4*)(&xr[qq * 64 + 4 * i]);
      { float is = 1.f / s4.x; float df = (x4.x - m4.x) * is; s2 += df * df; ls += __logf(s4.x); }
      { float is = 1.f / s4.y; float df = (x4.y - m4.y) * is; s2 += df * df; ls += __logf(s4.y); }
      { float is = 1.f / s4.z; float df = (x4.z - m4.z) * is; s2 += df * df; ls += __logf(s4.z); }
      { float is = 1.f / s4.w; float df = (x4.w - m4.w) * is; s2 += df * df; ls += __logf(s4.w); }
    }
    part[tid] = -0.5f * s2 - ls;
  }
  __syncthreads();

  if (tid < 64) {                      // exact top-32 + softmax (wave 0)
    float lp0 = part[l * 4] + part[l * 4 + 1] + part[l * 4 + 2] +
                part[l * 4 + 3] - LOG2PI_TERM;
    u32 ext = (fkey(lp0) & 0xFFFFFFC0u) | (u32)l;
    float maxlp = 0.f, ssum = 0.f;
    for (int it = 0; it < 32; ++it) {
      u32 m = ext;
      REDUCE_MAX(m)
      int j = (int)(m & 63u);
      u32 vb = m & 0xFFFFFFC0u;
      vb ^= (vb >> 31) ? 0x80000000u : 0xFFFFFFFFu;
      float lp = __uint_as_float(vb);
      if (it == 0) maxlp = lp;
      float e = __expf(lp - maxlp);
      ssum += e;
      if (l == 0) { ew[it] = e; kf[it] = selk[j]; }
      if (j == l) ext = 0;
    }
    if (l == 0) invs_sh = 1.0f / ssum;
  }
  __syncthreads();
#undef REDUCE_MAX

  {  // weighted gather: one output element per thread
    float a = 0.f;
    for (int i = 0; i < 32; ++i)
      a += ew[i] * outs[(size_t)kf[i] * ODIM + tid];
    out[(size_t)row * ODIM + tid] = a * invs_sh;
  }
}

// ---------------------------------------------------------------------------
extern "C" void kernel_launch(void* const* d_in, const int* in_sizes, int n_in,
                              void* d_out, int out_size, void* d_ws, size_t ws_size,
                              hipStream_t stream) {
  const float* x = (const float*)d_in[0];
  const float* mean = (const float*)d_in[1];
  const float* stdd = (const float*)d_in[2];
  const float* outs = (const float*)d_in[3];
  char* ws = (char*)d_ws;
  u16* A_ws = (u16*)(ws + WS_A);
  u32* ckey = (u32*)(ws + WS_KEY);

  prep_A<<<64, 256, 0, stream>>>(x, A_ws);
  main_gemm<<<NBLK, 512, 0, stream>>>(A_ws, mean, stdd, ckey);
  finalize<<<BROWS, 256, 0, stream>>>(x, mean, stdd, outs, ckey,
                                      (float*)d_out);
}